// Round 1
// baseline (219.034 us; speedup 1.0000x reference)
//
#include <hip/hip_runtime.h>
#include <hip/hip_bf16.h>
#include <stdint.h>

#define T_DIM 12
#define N_DIM 2048
#define B_DIM 16
#define C_IN  64
#define C_OUT 64
#define EMB   16
#define P_DIM 1024   // B_DIM*C_IN

typedef __attribute__((ext_vector_type(8))) short short8;
typedef __attribute__((ext_vector_type(4))) float f32x4;

static __device__ __forceinline__ unsigned short f2bf(float f) {
  union { float f; uint32_t u; } v; v.f = f;
  uint32_t u = v.u;
  return (unsigned short)((u + 0x7fffu + ((u >> 16) & 1u)) >> 16);
}

static __device__ __forceinline__ float sigf(float x) {
  return __builtin_amdgcn_rcpf(1.0f + __expf(-x));
}

// async global->LDS, 16B per lane; lds ptr must be wave-uniform
static __device__ __forceinline__ void gload16(const void* g, void* l) {
  __builtin_amdgcn_global_load_lds(
      (const __attribute__((address_space(1))) unsigned int*)g,
      (__attribute__((address_space(3))) unsigned int*)l, 16, 0, 0);
}

template<bool MAX>
static __device__ __forceinline__ float block_red(float v, float* red) {
  #pragma unroll
  for (int o = 32; o > 0; o >>= 1) {
    float t = __shfl_down(v, o, 64);
    v = MAX ? fmaxf(v, t) : (v + t);
  }
  __syncthreads();
  if ((threadIdx.x & 63) == 0) red[threadIdx.x >> 6] = v;
  __syncthreads();
  float r = red[0];
  #pragma unroll
  for (int w = 1; w < 4; ++w) r = MAX ? fmaxf(r, red[w]) : (r + red[w]);
  return r;
}

// ---------------- stats: static row-sum d^-1/2, adaptive softmax row max/sumexp
__launch_bounds__(256)
__global__ void k_stats(const float* __restrict__ As, const float* __restrict__ E1,
                        const float* __restrict__ E2, float* __restrict__ dinv,
                        float* __restrict__ mx, float* __restrict__ se) {
  int n = blockIdx.x, tid = threadIdx.x;
  __shared__ float e1s[EMB];
  __shared__ float red[4];
  if (tid < EMB) e1s[tid] = E1[n * EMB + tid];
  __syncthreads();

  float rs = 0.f;
  #pragma unroll
  for (int i = 0; i < N_DIM / 256; ++i)
    rs += fmaxf(As[(size_t)n * N_DIM + i * 256 + tid], 0.f);

  float p[8];
  #pragma unroll
  for (int i = 0; i < 8; ++i) {
    int m = i * 256 + tid;
    float d = 0.f;
    #pragma unroll
    for (int e = 0; e < EMB; ++e) d += e1s[e] * E2[e * N_DIM + m];
    p[i] = fmaxf(d, 0.f);
  }
  float lmx = p[0];
  #pragma unroll
  for (int i = 1; i < 8; ++i) lmx = fmaxf(lmx, p[i]);
  float gmx = block_red<true>(lmx, red);
  float ls = 0.f;
  #pragma unroll
  for (int i = 0; i < 8; ++i) ls += expf(p[i] - gmx);
  float gse = block_red<false>(ls, red);
  float grs = block_red<false>(rs, red);
  if (tid == 0) {
    dinv[n] = rsqrtf(fmaxf(grs + 1.0f, 1e-12f));
    mx[n] = gmx;
    se[n] = gse;
  }
}

// ---------------- W^T (128 x 64) bf16
__launch_bounds__(256)
__global__ void k_wt(const float* __restrict__ W, unsigned short* __restrict__ WT) {
  int q = blockIdx.x * 256 + threadIdx.x;   // 8192
  int j = q >> 6, c = q & 63;
  WT[q] = f2bf(W[c * 128 + j]);
}

// ---------------- assemble A (2048x2048) in bf16
__launch_bounds__(256)
__global__ void k_abuild(const float* __restrict__ As, const float* __restrict__ E1,
                         const float* __restrict__ E2, const float* __restrict__ alpha,
                         const float* __restrict__ dinv, const float* __restrict__ mx,
                         const float* __restrict__ se, unsigned short* __restrict__ A) {
  int n = blockIdx.x, tid = threadIdx.x;
  __shared__ float e1s[EMB];
  if (tid < EMB) e1s[tid] = E1[n * EMB + tid];
  __syncthreads();
  float a = sigf(alpha[0]);
  float di_n = dinv[n], m_n = mx[n], inv_se = 1.f / se[n];
  float ca = a, cb = (1.f - a) * 0.5f;
  #pragma unroll
  for (int i = 0; i < 8; ++i) {
    int m = i * 256 + tid;
    float d = 0.f;
    #pragma unroll
    for (int e = 0; e < EMB; ++e) d += e1s[e] * E2[e * N_DIM + m];
    float soft = expf(fmaxf(d, 0.f) - m_n) * inv_se;
    float idm = (m == n) ? 1.f : 0.f;
    float sv = fmaxf(As[(size_t)n * N_DIM + m], 0.f) + idm;
    float val = ca * di_n * dinv[m] * sv + cb * (soft + idm);
    A[(size_t)n * N_DIM + m] = f2bf(val);
  }
}

// ---------------- x (t,m,p) f32 -> XT (t,p,m) bf16 via LDS tile transpose
__launch_bounds__(256)
__global__ void k_xt(const float* __restrict__ x, unsigned short* __restrict__ XT) {
  __shared__ float tile[64 * 65];
  int bid = blockIdx.x;
  int t = bid >> 9;          // 512 tiles per t (32 m-tiles x 16 p-tiles)
  int rem = bid & 511;
  int mt = rem >> 4, pt = rem & 15;
  int m0 = mt * 64, p0 = pt * 64;
  int tid = threadIdx.x;
  #pragma unroll
  for (int i = 0; i < 16; ++i) {
    int lin = i * 256 + tid;
    int mm = lin >> 6, pp = lin & 63;
    tile[pp * 65 + mm] = x[(size_t)(t * N_DIM + m0 + mm) * P_DIM + p0 + pp];
  }
  __syncthreads();
  #pragma unroll
  for (int i = 0; i < 4; ++i) {
    int lin = i * 1024 + tid * 4;
    int pp = lin >> 6, mmb = lin & 63;
    union { unsigned short s[4]; uint64_t u; } pk;
    #pragma unroll
    for (int q = 0; q < 4; ++q) pk.s[q] = f2bf(tile[pp * 65 + mmb + q]);
    *(uint64_t*)&XT[(size_t)t * P_DIM * N_DIM + (size_t)(p0 + pp) * N_DIM + m0 + mmb] = pk.u;
  }
}

// ---------------- fused: Y_t = A @ X_t (bf16 MFMA), then Z = Y@Wfc+b, out = swiglu(Z)
#define BM 128
#define BN 128
#define BK 32
#define KSTEPS (N_DIM / BK)

__launch_bounds__(256)
__global__ void k_gemm(const unsigned short* __restrict__ A,   // 2048x2048 bf16
                       const unsigned short* __restrict__ XT,  // 12 x 1024 x 2048 bf16
                       const unsigned short* __restrict__ WT,  // 128 x 64 bf16
                       const float* __restrict__ bfc,          // 128 f32
                       float* __restrict__ out) {
  __shared__ unsigned short Asm[BM * BK];   // 8 KB
  __shared__ unsigned short Bsm[BN * BK];   // 8 KB
  __shared__ unsigned short Ys[256 * 64];   // 32 KB

  int bid = blockIdx.x;
  int t = bid / 128;
  int rem = bid - t * 128;
  int mb = rem >> 3, pb = rem & 7;
  int n0 = mb * BM, p0 = pb * BN;
  int tid = threadIdx.x;
  int lane = tid & 63, wid = tid >> 6;
  int wr = wid >> 1, wc = wid & 1;

  const unsigned short* Ag = A + (size_t)n0 * N_DIM;
  const unsigned short* Bg = XT + (size_t)t * P_DIM * N_DIM + (size_t)p0 * N_DIM;

  int srow = tid >> 2;            // 0..63
  int skel = (tid & 3) * 8;       // k element offset within 32
  const unsigned short* ga0 = Ag + (size_t)srow * N_DIM + skel;
  const unsigned short* ga1 = ga0 + (size_t)64 * N_DIM;
  const unsigned short* gb0 = Bg + (size_t)srow * N_DIM + skel;
  const unsigned short* gb1 = gb0 + (size_t)64 * N_DIM;
  char* lA = (char*)Asm + wid * 1024;
  char* lB = (char*)Bsm + wid * 1024;

  const char* apA = (const char*)Asm + (wr * 64 + (lane & 15)) * 64 + (lane >> 4) * 16;
  const char* apB = (const char*)Bsm + (wc * 64 + (lane & 15)) * 64 + (lane >> 4) * 16;

  f32x4 acc[4][4];
  #pragma unroll
  for (int r = 0; r < 4; ++r)
    #pragma unroll
    for (int f = 0; f < 4; ++f) acc[r][f] = (f32x4){0.f, 0.f, 0.f, 0.f};

  for (int kt = 0; kt < KSTEPS; ++kt) {
    int k0 = kt * BK;
    gload16(ga0 + k0, lA);
    gload16(ga1 + k0, lA + 4096);
    gload16(gb0 + k0, lB);
    gload16(gb1 + k0, lB + 4096);
    __syncthreads();   // compiler drains vmcnt before barrier

    short8 af[4], bf[4];
    #pragma unroll
    for (int r = 0; r < 4; ++r) af[r] = *(const short8*)(apA + r * 1024);
    #pragma unroll
    for (int f = 0; f < 4; ++f) bf[f] = *(const short8*)(apB + f * 1024);
    #pragma unroll
    for (int r = 0; r < 4; ++r)
      #pragma unroll
      for (int f = 0; f < 4; ++f)
        acc[r][f] = __builtin_amdgcn_mfma_f32_16x16x32_bf16(af[r], bf[f], acc[r][f], 0, 0, 0);
    __syncthreads();
  }

  // ---- epilogue: Y -> LDS bf16; rows nb = n_local*2 + b_local, cols c = 0..63
  #pragma unroll
  for (int r = 0; r < 4; ++r) {
    int rowb = wr * 64 + r * 16 + ((lane >> 4) << 2);
    #pragma unroll
    for (int f = 0; f < 4; ++f) {
      int c = f * 16 + (lane & 15);
      #pragma unroll
      for (int reg = 0; reg < 4; ++reg) {
        int nb = (rowb + reg) * 2 + wc;
        Ys[nb * 64 + c] = f2bf(acc[r][f][reg]);
      }
    }
  }
  __syncthreads();

  // W^T fragments from global (L2-hot): 8 col-frags x 2 k-steps
  short8 wf[8][2];
  #pragma unroll
  for (int f2 = 0; f2 < 8; ++f2) {
    int j = f2 * 16 + (lane & 15);
    #pragma unroll
    for (int ks = 0; ks < 2; ++ks)
      wf[f2][ks] = *(const short8*)((const char*)WT + j * 128 + ks * 64 + (lane >> 4) * 16);
  }
  float bl[8];
  #pragma unroll
  for (int f2 = 0; f2 < 8; ++f2) bl[f2] = bfc[f2 * 16 + (lane & 15)];

  int b0 = pb * 2;
  #pragma unroll
  for (int r2 = 0; r2 < 4; ++r2) {
    int rbase = wid * 64 + r2 * 16;
    short8 a2[2];
    #pragma unroll
    for (int ks = 0; ks < 2; ++ks)
      a2[ks] = *(const short8*)((const char*)Ys + (rbase + (lane & 15)) * 128 + ks * 64 + (lane >> 4) * 16);
    f32x4 acc2[8];
    #pragma unroll
    for (int f2 = 0; f2 < 8; ++f2) {
      acc2[f2] = (f32x4){0.f, 0.f, 0.f, 0.f};
      acc2[f2] = __builtin_amdgcn_mfma_f32_16x16x32_bf16(a2[0], wf[f2][0], acc2[f2], 0, 0, 0);
      acc2[f2] = __builtin_amdgcn_mfma_f32_16x16x32_bf16(a2[1], wf[f2][1], acc2[f2], 0, 0, 0);
    }
    #pragma unroll
    for (int f2 = 0; f2 < 4; ++f2) {
      #pragma unroll
      for (int reg = 0; reg < 4; ++reg) {
        int nb = rbase + ((lane >> 4) << 2) + reg;
        float zl = acc2[f2][reg] + bl[f2];
        float zr = acc2[f2 + 4][reg] + bl[f2 + 4];
        float ov = zl * sigf(zr);
        int n = n0 + (nb >> 1);
        int b = b0 + (nb & 1);
        int co = f2 * 16 + (lane & 15);
        out[(size_t)((t * N_DIM + n) * B_DIM + b) * C_OUT + co] = ov;
      }
    }
  }
}

extern "C" void kernel_launch(void* const* d_in, const int* in_sizes, int n_in,
                              void* d_out, int out_size, void* d_ws, size_t ws_size,
                              hipStream_t stream) {
  const float* x  = (const float*)d_in[0];
  const float* As = (const float*)d_in[1];
  const float* E1 = (const float*)d_in[2];
  const float* E2 = (const float*)d_in[3];
  const float* al = (const float*)d_in[4];
  const float* W  = (const float*)d_in[5];
  const float* bf = (const float*)d_in[6];
  float* out = (float*)d_out;

  char* ws = (char*)d_ws;
  unsigned short* XT = (unsigned short*)ws;                       // 50,331,648 B
  unsigned short* Ab = (unsigned short*)(ws + 50331648);          //  8,388,608 B
  unsigned short* WT = (unsigned short*)(ws + 58720256);          //     16,384 B
  float* dinv = (float*)(ws + 58736640);
  float* mx   = (float*)(ws + 58744832);
  float* se   = (float*)(ws + 58753024);

  k_stats<<<dim3(2048), dim3(256), 0, stream>>>(As, E1, E2, dinv, mx, se);
  k_wt<<<dim3(32), dim3(256), 0, stream>>>(W, WT);
  k_abuild<<<dim3(2048), dim3(256), 0, stream>>>(As, E1, E2, al, dinv, mx, se, Ab);
  k_xt<<<dim3(6144), dim3(256), 0, stream>>>(x, XT);
  k_gemm<<<dim3(1536), dim3(256), 0, stream>>>(Ab, XT, WT, bf, out);
}

// Round 2
// 204.247 us; speedup vs baseline: 1.0724x; 1.0724x over previous
//
#include <hip/hip_runtime.h>
#include <hip/hip_bf16.h>
#include <stdint.h>

#define T_DIM 12
#define N_DIM 2048
#define B_DIM 16
#define C_IN  64
#define C_OUT 64
#define EMB   16
#define P_DIM 1024   // B_DIM*C_IN

typedef __attribute__((ext_vector_type(8))) short short8;
typedef __attribute__((ext_vector_type(4))) float f32x4;

static __device__ __forceinline__ unsigned short f2bf(float f) {
  union { float f; uint32_t u; } v; v.f = f;
  uint32_t u = v.u;
  return (unsigned short)((u + 0x7fffu + ((u >> 16) & 1u)) >> 16);
}

static __device__ __forceinline__ float sigf(float x) {
  return __builtin_amdgcn_rcpf(1.0f + __expf(-x));
}

// async global->LDS, 16B per lane; lds ptr must be wave-uniform
static __device__ __forceinline__ void gload16(const void* g, void* l) {
  __builtin_amdgcn_global_load_lds(
      (const __attribute__((address_space(1))) unsigned int*)g,
      (__attribute__((address_space(3))) unsigned int*)l, 16, 0, 0);
}

template<bool MAX>
static __device__ __forceinline__ float block_red(float v, float* red) {
  #pragma unroll
  for (int o = 32; o > 0; o >>= 1) {
    float t = __shfl_down(v, o, 64);
    v = MAX ? fmaxf(v, t) : (v + t);
  }
  __syncthreads();
  if ((threadIdx.x & 63) == 0) red[threadIdx.x >> 6] = v;
  __syncthreads();
  float r = red[0];
  #pragma unroll
  for (int w = 1; w < 4; ++w) r = MAX ? fmaxf(r, red[w]) : (r + red[w]);
  return r;
}

// ---------------- stats: static row-sum d^-1/2, adaptive softmax row max/sumexp
__launch_bounds__(256)
__global__ void k_stats(const float* __restrict__ As, const float* __restrict__ E1,
                        const float* __restrict__ E2, float* __restrict__ dinv,
                        float* __restrict__ mx, float* __restrict__ se) {
  int n = blockIdx.x, tid = threadIdx.x;
  __shared__ float e1s[EMB];
  __shared__ float red[4];
  if (tid < EMB) e1s[tid] = E1[n * EMB + tid];
  __syncthreads();

  float rs = 0.f;
  #pragma unroll
  for (int i = 0; i < N_DIM / 256; ++i)
    rs += fmaxf(As[(size_t)n * N_DIM + i * 256 + tid], 0.f);

  float p[8];
  #pragma unroll
  for (int i = 0; i < 8; ++i) {
    int m = i * 256 + tid;
    float d = 0.f;
    #pragma unroll
    for (int e = 0; e < EMB; ++e) d += e1s[e] * E2[e * N_DIM + m];
    p[i] = fmaxf(d, 0.f);
  }
  float lmx = p[0];
  #pragma unroll
  for (int i = 1; i < 8; ++i) lmx = fmaxf(lmx, p[i]);
  float gmx = block_red<true>(lmx, red);
  float ls = 0.f;
  #pragma unroll
  for (int i = 0; i < 8; ++i) ls += expf(p[i] - gmx);
  float gse = block_red<false>(ls, red);
  float grs = block_red<false>(rs, red);
  if (tid == 0) {
    dinv[n] = rsqrtf(fmaxf(grs + 1.0f, 1e-12f));
    mx[n] = gmx;
    se[n] = gse;
  }
}

// ---------------- W^T (128 x 64) bf16
__launch_bounds__(256)
__global__ void k_wt(const float* __restrict__ W, unsigned short* __restrict__ WT) {
  int q = blockIdx.x * 256 + threadIdx.x;   // 8192
  int j = q >> 6, c = q & 63;
  WT[q] = f2bf(W[c * 128 + j]);
}

// ---------------- assemble A (2048x2048) in bf16
__launch_bounds__(256)
__global__ void k_abuild(const float* __restrict__ As, const float* __restrict__ E1,
                         const float* __restrict__ E2, const float* __restrict__ alpha,
                         const float* __restrict__ dinv, const float* __restrict__ mx,
                         const float* __restrict__ se, unsigned short* __restrict__ A) {
  int n = blockIdx.x, tid = threadIdx.x;
  __shared__ float e1s[EMB];
  if (tid < EMB) e1s[tid] = E1[n * EMB + tid];
  __syncthreads();
  float a = sigf(alpha[0]);
  float di_n = dinv[n], m_n = mx[n], inv_se = 1.f / se[n];
  float ca = a, cb = (1.f - a) * 0.5f;
  #pragma unroll
  for (int i = 0; i < 8; ++i) {
    int m = i * 256 + tid;
    float d = 0.f;
    #pragma unroll
    for (int e = 0; e < EMB; ++e) d += e1s[e] * E2[e * N_DIM + m];
    float soft = expf(fmaxf(d, 0.f) - m_n) * inv_se;
    float idm = (m == n) ? 1.f : 0.f;
    float sv = fmaxf(As[(size_t)n * N_DIM + m], 0.f) + idm;
    float val = ca * di_n * dinv[m] * sv + cb * (soft + idm);
    A[(size_t)n * N_DIM + m] = f2bf(val);
  }
}

// ---------------- x (t,m,p) f32 -> XT (t,p,m) bf16 via LDS tile transpose
// read: float4 (16B/lane); write: uint4 = 8 bf16 (16B/lane)
__launch_bounds__(256)
__global__ void k_xt(const float* __restrict__ x, unsigned short* __restrict__ XT) {
  __shared__ float tile[64 * 65];
  int bid = blockIdx.x;
  int t = bid >> 9;          // 512 tiles per t (32 m-tiles x 16 p-tiles)
  int rem = bid & 511;
  int mt = rem >> 4, pt = rem & 15;
  int m0 = mt * 64, p0 = pt * 64;
  int tid = threadIdx.x;
  #pragma unroll
  for (int i = 0; i < 4; ++i) {
    int lin = i * 256 + tid;          // 0..1023
    int mm = lin >> 4;                // 0..63
    int pp4 = lin & 15;               // 0..15 (float4 along p)
    const float4 v = *(const float4*)&x[(size_t)(t * N_DIM + m0 + mm) * P_DIM + p0 + pp4 * 4];
    tile[(pp4 * 4 + 0) * 65 + mm] = v.x;
    tile[(pp4 * 4 + 1) * 65 + mm] = v.y;
    tile[(pp4 * 4 + 2) * 65 + mm] = v.z;
    tile[(pp4 * 4 + 3) * 65 + mm] = v.w;
  }
  __syncthreads();
  #pragma unroll
  for (int i = 0; i < 2; ++i) {
    int lin = i * 256 + tid;          // 0..511
    int pp = lin >> 3;                // 0..63
    int mmb = (lin & 7) * 8;          // 8 bf16 along m
    union { unsigned short s[8]; uint4 u; } pk;
    #pragma unroll
    for (int q = 0; q < 8; ++q) pk.s[q] = f2bf(tile[pp * 65 + mmb + q]);
    *(uint4*)&XT[(size_t)t * P_DIM * N_DIM + (size_t)(p0 + pp) * N_DIM + m0 + mmb] = pk.u;
  }
}

// ---------------- fused: Y_t = A @ X_t (bf16 MFMA), then Z = Y@Wfc+b, out = swiglu(Z)
#define BM 128
#define BN 128
#define BK 32
#define KSTEPS (N_DIM / BK)

__launch_bounds__(256)
__global__ void k_gemm(const unsigned short* __restrict__ A,   // 2048x2048 bf16
                       const unsigned short* __restrict__ XT,  // 12 x 1024 x 2048 bf16
                       const unsigned short* __restrict__ WT,  // 128 x 64 bf16
                       const float* __restrict__ bfc,          // 128 f32
                       float* __restrict__ out) {
  // 32 KB shared, time-multiplexed:
  //   main loop: Asm (8 KB) + Bsm (8 KB), epilogue: Ys (32 KB)
  __shared__ __align__(16) char smem[32768];
  unsigned short* Asm = (unsigned short*)smem;
  unsigned short* Bsm = (unsigned short*)(smem + 8192);
  unsigned short* Ys  = (unsigned short*)smem;

  int bid = blockIdx.x;
  int t = bid / 128;
  int rem = bid - t * 128;
  int mb = rem >> 3, pb = rem & 7;
  int n0 = mb * BM, p0 = pb * BN;
  int tid = threadIdx.x;
  int lane = tid & 63, wid = tid >> 6;
  int wr = wid >> 1, wc = wid & 1;

  const unsigned short* Ag = A + (size_t)n0 * N_DIM;
  const unsigned short* Bg = XT + (size_t)t * P_DIM * N_DIM + (size_t)p0 * N_DIM;

  int srow = tid >> 2;            // 0..63
  int skel = (tid & 3) * 8;       // k element offset within 32
  const unsigned short* ga0 = Ag + (size_t)srow * N_DIM + skel;
  const unsigned short* ga1 = ga0 + (size_t)64 * N_DIM;
  const unsigned short* gb0 = Bg + (size_t)srow * N_DIM + skel;
  const unsigned short* gb1 = gb0 + (size_t)64 * N_DIM;
  char* lA = (char*)Asm + wid * 1024;
  char* lB = (char*)Bsm + wid * 1024;

  const char* apA = (const char*)Asm + (wr * 64 + (lane & 15)) * 64 + (lane >> 4) * 16;
  const char* apB = (const char*)Bsm + (wc * 64 + (lane & 15)) * 64 + (lane >> 4) * 16;

  f32x4 acc[4][4];
  #pragma unroll
  for (int r = 0; r < 4; ++r)
    #pragma unroll
    for (int f = 0; f < 4; ++f) acc[r][f] = (f32x4){0.f, 0.f, 0.f, 0.f};

  for (int kt = 0; kt < KSTEPS; ++kt) {
    int k0 = kt * BK;
    gload16(ga0 + k0, lA);
    gload16(ga1 + k0, lA + 4096);
    gload16(gb0 + k0, lB);
    gload16(gb1 + k0, lB + 4096);
    __syncthreads();   // compiler drains vmcnt before barrier

    short8 af[4], bf[4];
    #pragma unroll
    for (int r = 0; r < 4; ++r) af[r] = *(const short8*)(apA + r * 1024);
    #pragma unroll
    for (int f = 0; f < 4; ++f) bf[f] = *(const short8*)(apB + f * 1024);
    #pragma unroll
    for (int r = 0; r < 4; ++r)
      #pragma unroll
      for (int f = 0; f < 4; ++f)
        acc[r][f] = __builtin_amdgcn_mfma_f32_16x16x32_bf16(af[r], bf[f], acc[r][f], 0, 0, 0);
    __syncthreads();
  }

  // ---- epilogue: Y -> LDS bf16 (overlays A/B tiles; all frag reads done
  // before the K-loop's final barrier, so the overwrite is safe)
  #pragma unroll
  for (int r = 0; r < 4; ++r) {
    int rowb = wr * 64 + r * 16 + ((lane >> 4) << 2);
    #pragma unroll
    for (int f = 0; f < 4; ++f) {
      int c = f * 16 + (lane & 15);
      #pragma unroll
      for (int reg = 0; reg < 4; ++reg) {
        int nb = (rowb + reg) * 2 + wc;
        Ys[nb * 64 + c] = f2bf(acc[r][f][reg]);
      }
    }
  }
  __syncthreads();

  // W^T fragments from global (L2-hot): 8 col-frags x 2 k-steps
  short8 wf[8][2];
  #pragma unroll
  for (int f2 = 0; f2 < 8; ++f2) {
    int j = f2 * 16 + (lane & 15);
    #pragma unroll
    for (int ks = 0; ks < 2; ++ks)
      wf[f2][ks] = *(const short8*)((const char*)WT + j * 128 + ks * 64 + (lane >> 4) * 16);
  }
  float bl[8];
  #pragma unroll
  for (int f2 = 0; f2 < 8; ++f2) bl[f2] = bfc[f2 * 16 + (lane & 15)];

  int b0 = pb * 2;
  #pragma unroll
  for (int r2 = 0; r2 < 4; ++r2) {
    int rbase = wid * 64 + r2 * 16;
    short8 a2[2];
    #pragma unroll
    for (int ks = 0; ks < 2; ++ks)
      a2[ks] = *(const short8*)((const char*)Ys + (rbase + (lane & 15)) * 128 + ks * 64 + (lane >> 4) * 16);
    f32x4 acc2[8];
    #pragma unroll
    for (int f2 = 0; f2 < 8; ++f2) {
      acc2[f2] = (f32x4){0.f, 0.f, 0.f, 0.f};
      acc2[f2] = __builtin_amdgcn_mfma_f32_16x16x32_bf16(a2[0], wf[f2][0], acc2[f2], 0, 0, 0);
      acc2[f2] = __builtin_amdgcn_mfma_f32_16x16x32_bf16(a2[1], wf[f2][1], acc2[f2], 0, 0, 0);
    }
    #pragma unroll
    for (int f2 = 0; f2 < 4; ++f2) {
      #pragma unroll
      for (int reg = 0; reg < 4; ++reg) {
        int nb = rbase + ((lane >> 4) << 2) + reg;
        float zl = acc2[f2][reg] + bl[f2];
        float zr = acc2[f2 + 4][reg] + bl[f2 + 4];
        float ov = zl * sigf(zr);
        int n = n0 + (nb >> 1);
        int b = b0 + (nb & 1);
        int co = f2 * 16 + (lane & 15);
        out[(size_t)((t * N_DIM + n) * B_DIM + b) * C_OUT + co] = ov;
      }
    }
  }
}

extern "C" void kernel_launch(void* const* d_in, const int* in_sizes, int n_in,
                              void* d_out, int out_size, void* d_ws, size_t ws_size,
                              hipStream_t stream) {
  const float* x  = (const float*)d_in[0];
  const float* As = (const float*)d_in[1];
  const float* E1 = (const float*)d_in[2];
  const float* E2 = (const float*)d_in[3];
  const float* al = (const float*)d_in[4];
  const float* W  = (const float*)d_in[5];
  const float* bf = (const float*)d_in[6];
  float* out = (float*)d_out;

  char* ws = (char*)d_ws;
  unsigned short* XT = (unsigned short*)ws;                       // 50,331,648 B
  unsigned short* Ab = (unsigned short*)(ws + 50331648);          //  8,388,608 B
  unsigned short* WT = (unsigned short*)(ws + 58720256);          //     16,384 B
  float* dinv = (float*)(ws + 58736640);
  float* mx   = (float*)(ws + 58744832);
  float* se   = (float*)(ws + 58753024);

  k_stats<<<dim3(2048), dim3(256), 0, stream>>>(As, E1, E2, dinv, mx, se);
  k_wt<<<dim3(32), dim3(256), 0, stream>>>(W, WT);
  k_abuild<<<dim3(2048), dim3(256), 0, stream>>>(As, E1, E2, al, dinv, mx, se, Ab);
  k_xt<<<dim3(6144), dim3(256), 0, stream>>>(x, XT);
  k_gemm<<<dim3(1536), dim3(256), 0, stream>>>(Ab, XT, WT, bf, out);
}